// Round 1
// baseline (18973.268 us; speedup 1.0000x reference)
//
#include <hip/hip_runtime.h>

#define N_ENT 50000
#define H 128
#define NREL 460
#define T_STEPS 8
#define NEDGE 600000
#define NLAYER 2
#define SLOPE 0.22916666666666666f
#define NCHUNK ((N_ENT + 31) / 32)

__device__ __forceinline__ float wave_sum(float v) {
#pragma unroll
  for (int off = 32; off > 0; off >>= 1) v += __shfl_xor(v, off, 64);
  return v;
}

// one wave per row (64 lanes x float2)
__global__ void l2norm_kernel(const float* __restrict__ in, float* __restrict__ out) {
  int row = blockIdx.x * 4 + (threadIdx.x >> 6);
  int lane = threadIdx.x & 63;
  size_t base = (size_t)row * H;
  float2 v = ((const float2*)(in + base))[lane];
  float ss = wave_sum(v.x * v.x + v.y * v.y);
  float inv = 1.0f / fmaxf(sqrtf(ss), 1e-12f);
  float2 o = {v.x * inv, v.y * inv};
  ((float2*)(out + base))[lane] = o;
}

__global__ void indeg_kernel(const int* __restrict__ dst, int* __restrict__ indeg) {
  int i = blockIdx.x * 256 + threadIdx.x;
  if (i < NEDGE) atomicAdd(&indeg[dst[i]], 1);
}

// 8 edges per 256-thread block; 32 lanes x float4 = 128 floats per edge
__global__ void edge_kernel(const float* __restrict__ h, const float* __restrict__ rel,
                            const int* __restrict__ src, const int* __restrict__ dst,
                            const int* __restrict__ ety, float* __restrict__ acc) {
  int e = blockIdx.x * 8 + (threadIdx.x >> 5);
  int q = threadIdx.x & 31;
  int s = src[e], d = dst[e], ty = ety[e];
  float4 hv = *(const float4*)(h + (size_t)s * H + q * 4);
  float4 rv = *(const float4*)(rel + (size_t)ty * H + q * 4);
  float* ap = acc + (size_t)d * H + q * 4;
  atomicAdd(ap + 0, hv.x + rv.x);
  atomicAdd(ap + 1, hv.y + rv.y);
  atomicAdd(ap + 2, hv.z + rv.z);
  atomicAdd(ap + 3, hv.w + rv.w);
}

// C[N,128] = epilogue(A[N,128] @ B[128,128])
// MODE 0: A scaled per-row by 1/max(indeg,1); write raw        (agg @ w_neigh)
// MODE 1: C = rrelu(aux + A@B)                                  (h @ w_loop + agg)
// MODE 2: C = sigmoid(A@B + bias(aux))                          (time gate)
template <int MODE>
__global__ __launch_bounds__(256) void gemm_kernel(
    const float* __restrict__ A, const float* __restrict__ B,
    const int* __restrict__ indeg, const float* __restrict__ aux,
    float* __restrict__ C) {
  __shared__ float Bs[H][H];   // 64 KB
  __shared__ float As[H][32];  // 16 KB, transposed A tile
  int tid = threadIdx.x;
#pragma unroll
  for (int i = 0; i < 16; i++) {
    int f = tid + i * 256;
    ((float4*)Bs)[f] = ((const float4*)B)[f];
  }
  int cg = tid & 31;   // cols cg*4 .. cg*4+3
  int rq = tid >> 5;   // rows rq*4 .. rq*4+3 within 32-row chunk
  for (int chunk = blockIdx.x; chunk < NCHUNK; chunk += gridDim.x) {
    int row0 = chunk * 32;
    __syncthreads();  // also covers initial Bs load
#pragma unroll
    for (int i = 0; i < 4; i++) {
      int f = tid + i * 256;        // float4 index in 32x128 tile
      int r = f >> 5, c4 = f & 31;
      float4 v = {0.f, 0.f, 0.f, 0.f};
      if (row0 + r < N_ENT) {
        v = *(const float4*)(A + (size_t)(row0 + r) * H + c4 * 4);
        if (MODE == 0) {
          int dg = indeg[row0 + r];
          float nm = 1.0f / (float)(dg > 0 ? dg : 1);
          v.x *= nm; v.y *= nm; v.z *= nm; v.w *= nm;
        }
      }
      As[c4 * 4 + 0][r] = v.x; As[c4 * 4 + 1][r] = v.y;
      As[c4 * 4 + 2][r] = v.z; As[c4 * 4 + 3][r] = v.w;
    }
    __syncthreads();
    float accr[4][4] = {};
#pragma unroll 8
    for (int k = 0; k < H; k++) {
      float4 a = *(const float4*)&As[k][rq * 4];
      float4 b = *(const float4*)&Bs[k][cg * 4];
      float av[4] = {a.x, a.y, a.z, a.w};
      float bv[4] = {b.x, b.y, b.z, b.w};
#pragma unroll
      for (int r = 0; r < 4; r++)
#pragma unroll
        for (int c = 0; c < 4; c++)
          accr[r][c] = fmaf(av[r], bv[c], accr[r][c]);
    }
#pragma unroll
    for (int r = 0; r < 4; r++) {
      int gr = row0 + rq * 4 + r;
      if (gr >= N_ENT) break;
      float4 o = {accr[r][0], accr[r][1], accr[r][2], accr[r][3]};
      if (MODE == 1) {
        float4 tv = *(const float4*)(aux + (size_t)gr * H + cg * 4);
        o.x += tv.x; o.y += tv.y; o.z += tv.z; o.w += tv.w;
        o.x = o.x >= 0.f ? o.x : SLOPE * o.x;
        o.y = o.y >= 0.f ? o.y : SLOPE * o.y;
        o.z = o.z >= 0.f ? o.z : SLOPE * o.z;
        o.w = o.w >= 0.f ? o.w : SLOPE * o.w;
      } else if (MODE == 2) {
        float4 bv = *(const float4*)(aux + cg * 4);
        o.x = 1.0f / (1.0f + expf(-(o.x + bv.x)));
        o.y = 1.0f / (1.0f + expf(-(o.y + bv.y)));
        o.z = 1.0f / (1.0f + expf(-(o.z + bv.z)));
        o.w = 1.0f / (1.0f + expf(-(o.w + bv.w)));
      }
      *(float4*)(C + (size_t)gr * H + cg * 4) = o;
    }
  }
}

// rare rows with indeg==0 use w_evolve instead of w_loop
__global__ void fixup_kernel(const float* __restrict__ h_in, const float* __restrict__ tmp,
                             const float* __restrict__ We, const int* __restrict__ indeg,
                             float* __restrict__ out) {
  for (int r = blockIdx.x; r < N_ENT; r += gridDim.x) {
    if (indeg[r] != 0) continue;
    int lane = threadIdx.x;
#pragma unroll
    for (int cc = 0; cc < 2; cc++) {
      int c = lane + cc * 64;
      float s = 0.f;
      for (int k = 0; k < H; k++) s += h_in[(size_t)r * H + k] * We[(size_t)k * H + c];
      float z = tmp[(size_t)r * H + c] + s;
      out[(size_t)r * H + c] = z >= 0.f ? z : SLOPE * z;
    }
  }
}

// out = g * l2norm(h2) + (1-g) * h_prev  (one wave per row)
__global__ void combine_kernel(const float* __restrict__ h2, const float* __restrict__ g,
                               const float* __restrict__ hprev, float* __restrict__ out) {
  int row = blockIdx.x * 4 + (threadIdx.x >> 6);
  int lane = threadIdx.x & 63;
  size_t base = (size_t)row * H;
  float2 v = ((const float2*)(h2 + base))[lane];
  float ss = wave_sum(v.x * v.x + v.y * v.y);
  float inv = 1.0f / fmaxf(sqrtf(ss), 1e-12f);
  float2 gv = ((const float2*)(g + base))[lane];
  float2 hp = ((const float2*)(hprev + base))[lane];
  float2 o;
  o.x = gv.x * (v.x * inv) + (1.0f - gv.x) * hp.x;
  o.y = gv.y * (v.y * inv) + (1.0f - gv.y) * hp.y;
  ((float2*)(out + base))[lane] = o;
}

extern "C" void kernel_launch(void* const* d_in, const int* in_sizes, int n_in,
                              void* d_out, int out_size, void* d_ws, size_t ws_size,
                              hipStream_t stream) {
  const float* emb_ent  = (const float*)d_in[0];
  const float* emb_rel  = (const float*)d_in[1];
  const float* w_neigh  = (const float*)d_in[2];
  const float* w_loop   = (const float*)d_in[3];
  const float* w_evolve = (const float*)d_in[4];
  const float* tg_w     = (const float*)d_in[5];
  const float* tg_b     = (const float*)d_in[6];
  const int* src = (const int*)d_in[7];
  const int* dst = (const int*)d_in[8];
  const int* ety = (const int*)d_in[9];
  float* out = (float*)d_out;

  const size_t NH = (size_t)N_ENT * H;
  char* w = (char*)d_ws;
  int* indeg = (int*)w;   w += (((size_t)N_ENT * 4 + 255) & ~(size_t)255);
  float* acc = (float*)w; w += NH * 4;
  float* tmp = (float*)w; w += NH * 4;
  float* hA  = (float*)w; w += NH * 4;
  float* hB  = acc;  // alias: acc's last read (gemm<0> of layer 1) precedes hB's write
                     // (gemm<1> of layer 1); hB consumed by combine before next memset.

  // emb_rel passthrough output
  hipMemcpyAsync(out + (size_t)(T_STEPS + 1) * NH, emb_rel, (size_t)NREL * H * 4,
                 hipMemcpyDeviceToDevice, stream);
  // h0 = l2norm(emb_ent) -> history slot 0
  l2norm_kernel<<<N_ENT / 4, 256, 0, stream>>>(emb_ent, out);

  for (int t = 0; t < T_STEPS; t++) {
    float* h_t = out + (size_t)t * NH;
    float* h_n = out + (size_t)(t + 1) * NH;
    const int* st = src + (size_t)t * NEDGE;
    const int* dt = dst + (size_t)t * NEDGE;
    const int* et = ety + (size_t)t * NEDGE;

    hipMemsetAsync(indeg, 0, (size_t)N_ENT * 4, stream);
    indeg_kernel<<<(NEDGE + 255) / 256, 256, 0, stream>>>(dt, indeg);

    const float* hin = h_t;
    for (int l = 0; l < NLAYER; l++) {
      float* hout = (l == 0) ? hA : hB;
      hipMemsetAsync(acc, 0, NH * 4, stream);
      edge_kernel<<<NEDGE / 8, 256, 0, stream>>>(hin, emb_rel, st, dt, et, acc);
      // tmp = (acc * norm) @ w_neigh[l]
      gemm_kernel<0><<<512, 256, 0, stream>>>(acc, w_neigh + (size_t)l * H * H, indeg, nullptr, tmp);
      // hout = rrelu(tmp + hin @ w_loop[l])
      gemm_kernel<1><<<512, 256, 0, stream>>>(hin, w_loop + (size_t)l * H * H, nullptr, tmp, hout);
      // rows with indeg==0: hout = rrelu(tmp + hin @ w_evolve[l])
      fixup_kernel<<<256, 64, 0, stream>>>(hin, tmp, w_evolve + (size_t)l * H * H, indeg, hout);
      hin = hout;
    }
    // tmp = sigmoid(h_t @ tg_w + tg_b)   (time gate, reuses tmp)
    gemm_kernel<2><<<512, 256, 0, stream>>>(h_t, tg_w, nullptr, tg_b, tmp);
    // h_{t+1} = g * l2norm(hB) + (1-g) * h_t
    combine_kernel<<<N_ENT / 4, 256, 0, stream>>>(hB, tmp, h_t, h_n);
  }
}

// Round 2
// 3799.951 us; speedup vs baseline: 4.9930x; 4.9930x over previous
//
#include <hip/hip_runtime.h>

#define N_ENT 50000
#define H 128
#define NREL 460
#define T_STEPS 8
#define NEDGE 600000
#define NLAYER 2
#define SLOPE 0.22916666666666666f
#define NCHUNK ((N_ENT + 31) / 32)

__device__ __forceinline__ float wave_sum(float v) {
#pragma unroll
  for (int off = 32; off > 0; off >>= 1) v += __shfl_xor(v, off, 64);
  return v;
}

// one wave per row (64 lanes x float2)
__global__ void l2norm_kernel(const float* __restrict__ in, float* __restrict__ out) {
  int row = blockIdx.x * 4 + (threadIdx.x >> 6);
  int lane = threadIdx.x & 63;
  size_t base = (size_t)row * H;
  float2 v = ((const float2*)(in + base))[lane];
  float ss = wave_sum(v.x * v.x + v.y * v.y);
  float inv = 1.0f / fmaxf(sqrtf(ss), 1e-12f);
  float2 o = {v.x * inv, v.y * inv};
  ((float2*)(out + base))[lane] = o;
}

__global__ void indeg_kernel(const int* __restrict__ dst, int* __restrict__ rp) {
  int i = blockIdx.x * 256 + threadIdx.x;
  if (i < NEDGE) atomicAdd(&rp[dst[i]], 1);
}

// single-block exclusive scan over rp[0..N_ENT-1]
__global__ __launch_bounds__(256) void scan_kernel(int* __restrict__ rp) {
  __shared__ int sums[256];
  const int CPT = (N_ENT + 255) / 256;  // 196
  int tid = threadIdx.x;
  int begin = tid * CPT;
  int end = begin + CPT < N_ENT ? begin + CPT : N_ENT;
  int s0 = 0, s1 = 0, s2 = 0, s3 = 0;
  int i = begin;
  for (; i + 4 <= end; i += 4) {
    s0 += rp[i]; s1 += rp[i + 1]; s2 += rp[i + 2]; s3 += rp[i + 3];
  }
  for (; i < end; i++) s0 += rp[i];
  sums[tid] = s0 + s1 + s2 + s3;
  __syncthreads();
  for (int off = 1; off < 256; off <<= 1) {
    int v = (tid >= off) ? sums[tid - off] : 0;
    __syncthreads();
    sums[tid] += v;
    __syncthreads();
  }
  int prefix = (tid == 0) ? 0 : sums[tid - 1];
#pragma unroll 4
  for (i = begin; i < end; i++) {
    int v = rp[i];
    rp[i] = prefix;
    prefix += v;
  }
}

// scatter edges to CSR order; advances rp[d] so that afterwards
// rp[d] == exclusive_prefix[d+1]  (row d spans [d? rp[d-1]:0, rp[d]))
__global__ void scatter_kernel(const int* __restrict__ src, const int* __restrict__ dst,
                               const int* __restrict__ ety, int* __restrict__ rp,
                               int2* __restrict__ edges) {
  int i = blockIdx.x * 256 + threadIdx.x;
  if (i < NEDGE) {
    int d = dst[i];
    int pos = atomicAdd(&rp[d], 1);
    edges[pos] = make_int2(src[i], ety[i]);
  }
}

// one 32-lane half-wave per destination row: agg[d] = (1/max(deg,1)) * sum(h[s]+rel[ty])
__global__ __launch_bounds__(256) void gather_kernel(
    const float* __restrict__ h, const float* __restrict__ rel,
    const int* __restrict__ rp, const int2* __restrict__ edges,
    float* __restrict__ agg) {
  int d = blockIdx.x * 8 + (threadIdx.x >> 5);
  int q = threadIdx.x & 31;
  int start = (d == 0) ? 0 : rp[d - 1];
  int end = rp[d];
  float4 a = {0.f, 0.f, 0.f, 0.f};
  for (int i = start; i < end; i++) {
    int2 se = edges[i];
    float4 hv = *(const float4*)(h + (size_t)se.x * H + q * 4);
    float4 rv = *(const float4*)(rel + (size_t)se.y * H + q * 4);
    a.x += hv.x + rv.x; a.y += hv.y + rv.y;
    a.z += hv.z + rv.z; a.w += hv.w + rv.w;
  }
  int deg = end - start;
  float nm = 1.0f / (float)(deg > 0 ? deg : 1);
  float4 o = {a.x * nm, a.y * nm, a.z * nm, a.w * nm};
  *(float4*)(agg + (size_t)d * H + q * 4) = o;
}

// C = rrelu(A1 @ B1 + A2 @ B2); A-tiles staged in LDS (conflict-free layout),
// B matrices streamed through L1/L2. One 32-row chunk per block.
__global__ __launch_bounds__(256) void rgcn_gemm(
    const float* __restrict__ A1, const float* __restrict__ A2,
    const float* __restrict__ B1, const float* __restrict__ B2,
    float* __restrict__ C) {
  __shared__ float As[H][32];
  __shared__ float Hs[H][32];
  int tid = threadIdx.x;
  int row0 = blockIdx.x * 32;
#pragma unroll
  for (int i = 0; i < 4; i++) {
    int f = tid + i * 256;
    int r = f & 31, c4 = f >> 5;
    int gr = row0 + r;
    float4 v1 = {0.f, 0.f, 0.f, 0.f}, v2 = {0.f, 0.f, 0.f, 0.f};
    if (gr < N_ENT) {
      v1 = *(const float4*)(A1 + (size_t)gr * H + c4 * 4);
      v2 = *(const float4*)(A2 + (size_t)gr * H + c4 * 4);
    }
    As[c4 * 4 + 0][r] = v1.x; As[c4 * 4 + 1][r] = v1.y;
    As[c4 * 4 + 2][r] = v1.z; As[c4 * 4 + 3][r] = v1.w;
    Hs[c4 * 4 + 0][r] = v2.x; Hs[c4 * 4 + 1][r] = v2.y;
    Hs[c4 * 4 + 2][r] = v2.z; Hs[c4 * 4 + 3][r] = v2.w;
  }
  __syncthreads();
  int cg = tid & 31, rq = tid >> 5;
  float acc[4][4] = {};
#pragma unroll 4
  for (int k = 0; k < H; k++) {
    float4 a1 = *(const float4*)&As[k][rq * 4];
    float4 a2 = *(const float4*)&Hs[k][rq * 4];
    float4 b1 = *(const float4*)(B1 + (size_t)k * H + cg * 4);
    float4 b2 = *(const float4*)(B2 + (size_t)k * H + cg * 4);
    float a1v[4] = {a1.x, a1.y, a1.z, a1.w};
    float a2v[4] = {a2.x, a2.y, a2.z, a2.w};
    float b1v[4] = {b1.x, b1.y, b1.z, b1.w};
    float b2v[4] = {b2.x, b2.y, b2.z, b2.w};
#pragma unroll
    for (int r = 0; r < 4; r++)
#pragma unroll
      for (int c = 0; c < 4; c++)
        acc[r][c] = fmaf(a2v[r], b2v[c], fmaf(a1v[r], b1v[c], acc[r][c]));
  }
#pragma unroll
  for (int r = 0; r < 4; r++) {
    int gr = row0 + rq * 4 + r;
    if (gr >= N_ENT) break;
    float4 o = {acc[r][0], acc[r][1], acc[r][2], acc[r][3]};
    o.x = o.x >= 0.f ? o.x : SLOPE * o.x;
    o.y = o.y >= 0.f ? o.y : SLOPE * o.y;
    o.z = o.z >= 0.f ? o.z : SLOPE * o.z;
    o.w = o.w >= 0.f ? o.w : SLOPE * o.w;
    *(float4*)(C + (size_t)gr * H + cg * 4) = o;
  }
}

// G = sigmoid(A @ B + bias)
__global__ __launch_bounds__(256) void gate_gemm(
    const float* __restrict__ A, const float* __restrict__ B,
    const float* __restrict__ bias, float* __restrict__ G) {
  __shared__ float As[H][32];
  int tid = threadIdx.x;
  int row0 = blockIdx.x * 32;
#pragma unroll
  for (int i = 0; i < 4; i++) {
    int f = tid + i * 256;
    int r = f & 31, c4 = f >> 5;
    int gr = row0 + r;
    float4 v = {0.f, 0.f, 0.f, 0.f};
    if (gr < N_ENT) v = *(const float4*)(A + (size_t)gr * H + c4 * 4);
    As[c4 * 4 + 0][r] = v.x; As[c4 * 4 + 1][r] = v.y;
    As[c4 * 4 + 2][r] = v.z; As[c4 * 4 + 3][r] = v.w;
  }
  __syncthreads();
  int cg = tid & 31, rq = tid >> 5;
  float acc[4][4] = {};
#pragma unroll 4
  for (int k = 0; k < H; k++) {
    float4 a = *(const float4*)&As[k][rq * 4];
    float4 b = *(const float4*)(B + (size_t)k * H + cg * 4);
    float av[4] = {a.x, a.y, a.z, a.w};
    float bv[4] = {b.x, b.y, b.z, b.w};
#pragma unroll
    for (int r = 0; r < 4; r++)
#pragma unroll
      for (int c = 0; c < 4; c++)
        acc[r][c] = fmaf(av[r], bv[c], acc[r][c]);
  }
  float4 bv = *(const float4*)(bias + cg * 4);
#pragma unroll
  for (int r = 0; r < 4; r++) {
    int gr = row0 + rq * 4 + r;
    if (gr >= N_ENT) break;
    float4 o = {acc[r][0] + bv.x, acc[r][1] + bv.y, acc[r][2] + bv.z, acc[r][3] + bv.w};
    o.x = 1.0f / (1.0f + expf(-o.x));
    o.y = 1.0f / (1.0f + expf(-o.y));
    o.z = 1.0f / (1.0f + expf(-o.z));
    o.w = 1.0f / (1.0f + expf(-o.w));
    *(float4*)(G + (size_t)gr * H + cg * 4) = o;
  }
}

// rare rows with indeg==0: agg==0 there, so out = rrelu(h @ We)
__global__ void fixup_kernel(const float* __restrict__ h_in, const float* __restrict__ We,
                             const int* __restrict__ rp, float* __restrict__ out) {
  for (int r = blockIdx.x; r < N_ENT; r += gridDim.x) {
    int start = (r == 0) ? 0 : rp[r - 1];
    int end = rp[r];
    if (end > start) continue;
    int lane = threadIdx.x;
#pragma unroll
    for (int cc = 0; cc < 2; cc++) {
      int c = lane + cc * 64;
      float s = 0.f;
      for (int k = 0; k < H; k++) s += h_in[(size_t)r * H + k] * We[(size_t)k * H + c];
      out[(size_t)r * H + c] = s >= 0.f ? s : SLOPE * s;
    }
  }
}

// out = g * l2norm(h2) + (1-g) * h_prev  (one wave per row)
__global__ void combine_kernel(const float* __restrict__ h2, const float* __restrict__ g,
                               const float* __restrict__ hprev, float* __restrict__ out) {
  int row = blockIdx.x * 4 + (threadIdx.x >> 6);
  int lane = threadIdx.x & 63;
  size_t base = (size_t)row * H;
  float2 v = ((const float2*)(h2 + base))[lane];
  float ss = wave_sum(v.x * v.x + v.y * v.y);
  float inv = 1.0f / fmaxf(sqrtf(ss), 1e-12f);
  float2 gv = ((const float2*)(g + base))[lane];
  float2 hp = ((const float2*)(hprev + base))[lane];
  float2 o;
  o.x = gv.x * (v.x * inv) + (1.0f - gv.x) * hp.x;
  o.y = gv.y * (v.y * inv) + (1.0f - gv.y) * hp.y;
  ((float2*)(out + base))[lane] = o;
}

extern "C" void kernel_launch(void* const* d_in, const int* in_sizes, int n_in,
                              void* d_out, int out_size, void* d_ws, size_t ws_size,
                              hipStream_t stream) {
  const float* emb_ent  = (const float*)d_in[0];
  const float* emb_rel  = (const float*)d_in[1];
  const float* w_neigh  = (const float*)d_in[2];
  const float* w_loop   = (const float*)d_in[3];
  const float* w_evolve = (const float*)d_in[4];
  const float* tg_w     = (const float*)d_in[5];
  const float* tg_b     = (const float*)d_in[6];
  const int* src = (const int*)d_in[7];
  const int* dst = (const int*)d_in[8];
  const int* ety = (const int*)d_in[9];
  float* out = (float*)d_out;

  const size_t NH = (size_t)N_ENT * H;
  const size_t HH = (size_t)H * H;
  char* w = (char*)d_ws;
  int* rp = (int*)w;       w += (((size_t)N_ENT * 4 + 255) & ~(size_t)255);
  int2* edges = (int2*)w;  w += (((size_t)NEDGE * 8 + 255) & ~(size_t)255);
  float* agg = (float*)w;  w += NH * 4;
  float* hA  = (float*)w;  w += NH * 4;
  float* hB  = agg;  // in-place: rgcn_gemm stages each 32-row agg chunk into LDS
                     // before writing those same C rows; no cross-block reads.
  float* gate = hA;  // gate_gemm reads only h_t; runs after last reader of hA.

  // emb_rel passthrough output
  hipMemcpyAsync(out + (size_t)(T_STEPS + 1) * NH, emb_rel, (size_t)NREL * H * 4,
                 hipMemcpyDeviceToDevice, stream);
  // h0 = l2norm(emb_ent) -> history slot 0
  l2norm_kernel<<<N_ENT / 4, 256, 0, stream>>>(emb_ent, out);

  for (int t = 0; t < T_STEPS; t++) {
    float* h_t = out + (size_t)t * NH;
    float* h_n = out + (size_t)(t + 1) * NH;
    const int* st = src + (size_t)t * NEDGE;
    const int* dt = dst + (size_t)t * NEDGE;
    const int* et = ety + (size_t)t * NEDGE;

    // --- build CSR for this timestep ---
    hipMemsetAsync(rp, 0, (size_t)N_ENT * 4, stream);
    indeg_kernel<<<(NEDGE + 255) / 256, 256, 0, stream>>>(dt, rp);
    scan_kernel<<<1, 256, 0, stream>>>(rp);
    scatter_kernel<<<(NEDGE + 255) / 256, 256, 0, stream>>>(st, dt, et, rp, edges);

    // --- layer 0 ---
    gather_kernel<<<N_ENT / 8, 256, 0, stream>>>(h_t, emb_rel, rp, edges, agg);
    rgcn_gemm<<<NCHUNK, 256, 0, stream>>>(agg, h_t, w_neigh, w_loop, hA);
    fixup_kernel<<<256, 64, 0, stream>>>(h_t, w_evolve, rp, hA);
    // --- layer 1 ---
    gather_kernel<<<N_ENT / 8, 256, 0, stream>>>(hA, emb_rel, rp, edges, agg);
    rgcn_gemm<<<NCHUNK, 256, 0, stream>>>(agg, hA, w_neigh + HH, w_loop + HH, hB);
    fixup_kernel<<<256, 64, 0, stream>>>(hA, w_evolve + HH, rp, hB);

    // --- time gate + combine ---
    gate_gemm<<<NCHUNK, 256, 0, stream>>>(h_t, tg_w, tg_b, gate);
    combine_kernel<<<N_ENT / 4, 256, 0, stream>>>(hB, gate, h_t, h_n);
  }
}

// Round 3
// 3103.973 us; speedup vs baseline: 6.1126x; 1.2242x over previous
//
#include <hip/hip_runtime.h>

#define N_ENT 50000
#define H 128
#define NREL 460
#define T_STEPS 8
#define NEDGE 600000
#define SLOPE 0.22916666666666666f
#define NB196 196  // ceil(N_ENT/256)

typedef __attribute__((ext_vector_type(8))) short bf16x8;
typedef __attribute__((ext_vector_type(4))) float f32x4;
typedef unsigned short u16;
typedef unsigned int u32;

__device__ __forceinline__ float b2f(u16 u) {
  union { u32 i; float f; } v; v.i = ((u32)u) << 16; return v.f;
}
__device__ __forceinline__ u16 f2b(float f) {
  union { float f; u32 i; } v; v.f = f;
  return (u16)((v.i + 0x7FFFu + ((v.i >> 16) & 1u)) >> 16);
}

__device__ __forceinline__ float wave_sum(float v) {
#pragma unroll
  for (int off = 32; off > 0; off >>= 1) v += __shfl_xor(v, off, 64);
  return v;
}

// ---------- weight prep: bf16 transposed [n][k], 5 matrices ----------
__global__ void convw_kernel(const float* __restrict__ wn, const float* __restrict__ wl,
                             const float* __restrict__ tg, u16* __restrict__ wbt) {
  int m = blockIdx.x >> 6;                       // 64 blocks of 256 per matrix
  int f = ((blockIdx.x & 63) << 8) + threadIdx.x;  // 0..16383
  int n = f >> 7, k = f & 127;
  const float* src;
  switch (m) {
    case 0: src = wn; break;          // w_neigh[0]
    case 1: src = wl; break;          // w_loop[0]
    case 2: src = wn + 16384; break;  // w_neigh[1]
    case 3: src = wl + 16384; break;  // w_loop[1]
    default: src = tg; break;         // tg_w
  }
  wbt[m * 16384 + n * 128 + k] = f2b(src[k * 128 + n]);
}

// ---------- h0 = l2norm(emb_ent), f32 + bf16 ----------
__global__ void l2norm_kernel(const float* __restrict__ in, float* __restrict__ out,
                              u16* __restrict__ outb) {
  int row = blockIdx.x * 4 + (threadIdx.x >> 6);
  int lane = threadIdx.x & 63;
  size_t base = (size_t)row * H;
  float2 v = ((const float2*)(in + base))[lane];
  float ss = wave_sum(v.x * v.x + v.y * v.y);
  float inv = 1.0f / fmaxf(sqrtf(ss), 1e-12f);
  float2 o = {v.x * inv, v.y * inv};
  ((float2*)(out + base))[lane] = o;
  ushort2 ob; ob.x = f2b(o.x); ob.y = f2b(o.y);
  ((ushort2*)(outb + base))[lane] = ob;
}

// ---------- batched CSR build (all 8 timesteps) ----------
__global__ void indeg_all(const int* __restrict__ dst, int* __restrict__ rp8) {
  int t = blockIdx.y;
  int i = blockIdx.x * 256 + threadIdx.x;
  if (i < NEDGE) atomicAdd(&rp8[t * N_ENT + dst[(size_t)t * NEDGE + i]], 1);
}

__global__ __launch_bounds__(256) void reduce_all(const int* __restrict__ rp8,
                                                  int* __restrict__ bsum8) {
  int t = blockIdx.y, b = blockIdx.x, tid = threadIdx.x;
  int i = b * 256 + tid;
  int v = (i < N_ENT) ? rp8[t * N_ENT + i] : 0;
#pragma unroll
  for (int off = 32; off > 0; off >>= 1) v += __shfl_xor(v, off, 64);
  __shared__ int ls[4];
  if ((tid & 63) == 0) ls[tid >> 6] = v;
  __syncthreads();
  if (tid == 0) bsum8[t * NB196 + b] = ls[0] + ls[1] + ls[2] + ls[3];
}

__global__ __launch_bounds__(256) void scan_sums_all(int* __restrict__ bsum8) {
  int t = blockIdx.x, tid = threadIdx.x;
  __shared__ int s[256];
  int v = (tid < NB196) ? bsum8[t * NB196 + tid] : 0;
  s[tid] = v;
  __syncthreads();
  for (int off = 1; off < 256; off <<= 1) {
    int u = (tid >= off) ? s[tid - off] : 0;
    __syncthreads();
    s[tid] += u;
    __syncthreads();
  }
  if (tid < NB196) bsum8[t * NB196 + tid] = s[tid] - v;  // exclusive
}

__global__ __launch_bounds__(256) void scan_apply_all(int* __restrict__ rp8,
                                                      const int* __restrict__ bsum8) {
  int t = blockIdx.y, b = blockIdx.x, tid = threadIdx.x;
  int i = b * 256 + tid;
  __shared__ int s[256];
  int v = (i < N_ENT) ? rp8[t * N_ENT + i] : 0;
  s[tid] = v;
  __syncthreads();
  for (int off = 1; off < 256; off <<= 1) {
    int u = (tid >= off) ? s[tid - off] : 0;
    __syncthreads();
    s[tid] += u;
    __syncthreads();
  }
  if (i < N_ENT) rp8[t * N_ENT + i] = s[tid] - v + bsum8[t * NB196 + b];
}

// advances rp so afterwards rp[d] == end of row d
__global__ void scatter_all(const int* __restrict__ src, const int* __restrict__ dst,
                            const int* __restrict__ ety, int* rp8, u32* __restrict__ edges8) {
  int t = blockIdx.y;
  int i = blockIdx.x * 256 + threadIdx.x;
  if (i < NEDGE) {
    size_t o = (size_t)t * NEDGE + i;
    int d = dst[o];
    int pos = atomicAdd(&rp8[t * N_ENT + d], 1);
    edges8[(size_t)t * NEDGE + pos] = (u32)src[o] | ((u32)ety[o] << 17);
  }
}

// ---------- relsum[d] = sum_{e:dst=d} rel[ety_e]  (f32, layer-invariant) ----------
__global__ __launch_bounds__(256) void relsum_kernel(const float* __restrict__ rel,
                                                     const int* __restrict__ rp,
                                                     const u32* __restrict__ edges,
                                                     float* __restrict__ relsum) {
  int d = blockIdx.x * 8 + (threadIdx.x >> 5);
  int q = threadIdx.x & 31;
  int start = d ? rp[d - 1] : 0, end = rp[d];
  float4 a = {0.f, 0.f, 0.f, 0.f};
  for (int i = start; i < end; i++) {
    int ty = edges[i] >> 17;
    float4 rv = *(const float4*)(rel + (size_t)ty * H + q * 4);
    a.x += rv.x; a.y += rv.y; a.z += rv.z; a.w += rv.w;
  }
  *(float4*)(relsum + (size_t)d * H + q * 4) = a;
}

// ---------- agg[d] = (sum h[src] + relsum[d]) / max(deg,1), bf16 out ----------
__global__ __launch_bounds__(256) void gather_h(const u16* __restrict__ hb,
                                                const float* __restrict__ relsum,
                                                const int* __restrict__ rp,
                                                const u32* __restrict__ edges,
                                                u16* __restrict__ aggb) {
  int d = blockIdx.x * 8 + (threadIdx.x >> 5);
  int q = threadIdx.x & 31;
  int start = d ? rp[d - 1] : 0, end = rp[d];
  float a0 = 0.f, a1 = 0.f, a2 = 0.f, a3 = 0.f;
  for (int i = start; i < end; i++) {
    int s = edges[i] & 0x1FFFF;
    ushort4 hv = *(const ushort4*)(hb + (size_t)s * H + q * 4);
    a0 += b2f(hv.x); a1 += b2f(hv.y); a2 += b2f(hv.z); a3 += b2f(hv.w);
  }
  float4 rs = *(const float4*)(relsum + (size_t)d * H + q * 4);
  int deg = end - start;
  float nm = 1.0f / (float)(deg > 0 ? deg : 1);
  ushort4 o;
  o.x = f2b((a0 + rs.x) * nm); o.y = f2b((a1 + rs.y) * nm);
  o.z = f2b((a2 + rs.z) * nm); o.w = f2b((a3 + rs.w) * nm);
  *(ushort4*)(aggb + (size_t)d * H + q * 4) = o;
}

// ---------- C = rrelu(A1@B1 + A2@B2) via bf16 MFMA; OUT_MODE 0: bf16, 1: f32 ----------
template <int OUT_MODE>
__global__ __launch_bounds__(256) void rgcn_gemm_mfma(
    const u16* __restrict__ A1, const u16* __restrict__ A2,
    const u16* __restrict__ B1t, const u16* __restrict__ B2t,
    u16* Cb, float* Cf) {
  int wave = threadIdx.x >> 6, lane = threadIdx.x & 63;
  int row0 = blockIdx.x * 64 + wave * 16;
  int ar = lane & 15, kg = lane >> 4;
  int arow = row0 + ar;
  if (arow >= N_ENT) arow = 0;  // safe dummy row; stores are guarded
  bf16x8 a1[4], a2[4];
#pragma unroll
  for (int s = 0; s < 4; s++) {
    a1[s] = *(const bf16x8*)(A1 + (size_t)arow * H + s * 32 + kg * 8);
    a2[s] = *(const bf16x8*)(A2 + (size_t)arow * H + s * 32 + kg * 8);
  }
  f32x4 acc[8];
  f32x4 z = {0.f, 0.f, 0.f, 0.f};
#pragma unroll
  for (int n = 0; n < 8; n++) acc[n] = z;
#pragma unroll
  for (int n = 0; n < 8; n++) {
    const u16* b1p = B1t + (size_t)(n * 16 + ar) * H + kg * 8;
    const u16* b2p = B2t + (size_t)(n * 16 + ar) * H + kg * 8;
#pragma unroll
    for (int s = 0; s < 4; s++) {
      bf16x8 b1 = *(const bf16x8*)(b1p + s * 32);
      bf16x8 b2 = *(const bf16x8*)(b2p + s * 32);
      acc[n] = __builtin_amdgcn_mfma_f32_16x16x32_bf16(a1[s], b1, acc[n], 0, 0, 0);
      acc[n] = __builtin_amdgcn_mfma_f32_16x16x32_bf16(a2[s], b2, acc[n], 0, 0, 0);
    }
  }
#pragma unroll
  for (int n = 0; n < 8; n++) {
    int c = ar + n * 16;
#pragma unroll
    for (int r = 0; r < 4; r++) {
      int gr = row0 + kg * 4 + r;
      if (gr < N_ENT) {
        float v = acc[n][r];
        v = v >= 0.f ? v : SLOPE * v;
        if (OUT_MODE == 0) Cb[(size_t)gr * H + c] = f2b(v);
        else Cf[(size_t)gr * H + c] = v;
      }
    }
  }
}

// ---------- G = sigmoid(A@Bt + bias), bf16 out ----------
__global__ __launch_bounds__(256) void gate_gemm_mfma(
    const u16* __restrict__ A, const u16* __restrict__ Bt,
    const float* __restrict__ bias, u16* __restrict__ G) {
  int wave = threadIdx.x >> 6, lane = threadIdx.x & 63;
  int row0 = blockIdx.x * 64 + wave * 16;
  int ar = lane & 15, kg = lane >> 4;
  int arow = row0 + ar;
  if (arow >= N_ENT) arow = 0;
  bf16x8 a[4];
#pragma unroll
  for (int s = 0; s < 4; s++)
    a[s] = *(const bf16x8*)(A + (size_t)arow * H + s * 32 + kg * 8);
  f32x4 acc[8];
  f32x4 z = {0.f, 0.f, 0.f, 0.f};
#pragma unroll
  for (int n = 0; n < 8; n++) acc[n] = z;
#pragma unroll
  for (int n = 0; n < 8; n++) {
    const u16* bp = Bt + (size_t)(n * 16 + ar) * H + kg * 8;
#pragma unroll
    for (int s = 0; s < 4; s++) {
      bf16x8 b = *(const bf16x8*)(bp + s * 32);
      acc[n] = __builtin_amdgcn_mfma_f32_16x16x32_bf16(a[s], b, acc[n], 0, 0, 0);
    }
  }
#pragma unroll
  for (int n = 0; n < 8; n++) {
    int c = ar + n * 16;
    float bb = bias[c];
#pragma unroll
    for (int r = 0; r < 4; r++) {
      int gr = row0 + kg * 4 + r;
      if (gr < N_ENT) {
        float v = 1.0f / (1.0f + expf(-(acc[n][r] + bb)));
        G[(size_t)gr * H + c] = f2b(v);
      }
    }
  }
}

// ---------- deg==0 rows: out = rrelu(h @ We) (agg contribution is zero) ----------
template <int OUT_BF16>
__global__ void fixup_kernel(const u16* __restrict__ hin, const float* __restrict__ We,
                             const int* __restrict__ rp, u16* outb, float* outf) {
  for (int r = blockIdx.x; r < N_ENT; r += gridDim.x) {
    int start = r ? rp[r - 1] : 0;
    if (rp[r] > start) continue;
    int c = threadIdx.x;  // 128 threads
    float s = 0.f;
    for (int k = 0; k < H; k++) s += b2f(hin[(size_t)r * H + k]) * We[(size_t)k * H + c];
    s = s >= 0.f ? s : SLOPE * s;
    if (OUT_BF16) outb[(size_t)r * H + c] = f2b(s);
    else outf[(size_t)r * H + c] = s;
  }
}

// ---------- h_new = g*l2norm(h2) + (1-g)*h_prev ; h2 may alias out (in-place) ----------
__global__ void combine_kernel(const float* h2, const u16* __restrict__ g,
                               const float* __restrict__ hprev, float* out,
                               u16* __restrict__ outb) {
  int row = blockIdx.x * 4 + (threadIdx.x >> 6);
  int lane = threadIdx.x & 63;
  size_t base = (size_t)row * H;
  float2 v = ((const float2*)(h2 + base))[lane];
  float ss = wave_sum(v.x * v.x + v.y * v.y);
  float inv = 1.0f / fmaxf(sqrtf(ss), 1e-12f);
  ushort2 gv = ((const ushort2*)(g + base))[lane];
  float gx = b2f(gv.x), gy = b2f(gv.y);
  float2 hp = ((const float2*)(hprev + base))[lane];
  float ox = gx * (v.x * inv) + (1.0f - gx) * hp.x;
  float oy = gy * (v.y * inv) + (1.0f - gy) * hp.y;
  float2 o = {ox, oy};
  ((float2*)(out + base))[lane] = o;
  ushort2 ob; ob.x = f2b(ox); ob.y = f2b(oy);
  ((ushort2*)(outb + base))[lane] = ob;
}

extern "C" void kernel_launch(void* const* d_in, const int* in_sizes, int n_in,
                              void* d_out, int out_size, void* d_ws, size_t ws_size,
                              hipStream_t stream) {
  const float* emb_ent  = (const float*)d_in[0];
  const float* emb_rel  = (const float*)d_in[1];
  const float* w_neigh  = (const float*)d_in[2];
  const float* w_loop   = (const float*)d_in[3];
  const float* w_evolve = (const float*)d_in[4];
  const float* tg_w     = (const float*)d_in[5];
  const float* tg_b     = (const float*)d_in[6];
  const int* src = (const int*)d_in[7];
  const int* dst = (const int*)d_in[8];
  const int* ety = (const int*)d_in[9];
  float* out = (float*)d_out;

  const size_t NH = (size_t)N_ENT * H;
  auto au = [](size_t x) { return (x + 255) & ~(size_t)255; };
  char* w = (char*)d_ws;
  int* rp8 = (int*)w;      w += au((size_t)T_STEPS * N_ENT * 4);
  int* bsum8 = (int*)w;    w += au((size_t)T_STEPS * NB196 * 4);
  u32* edges8 = (u32*)w;   w += au((size_t)T_STEPS * NEDGE * 4);
  u16* aggb = (u16*)w;     w += au(NH * 2);
  u16* hAb = (u16*)w;      w += au(NH * 2);
  u16* hb = (u16*)w;       w += au(NH * 2);
  u16* gateb = (u16*)w;    w += au(NH * 2);
  u16* wbt = (u16*)w;      w += au((size_t)5 * 16384 * 2);

  // emb_rel passthrough
  hipMemcpyAsync(out + (size_t)(T_STEPS + 1) * NH, emb_rel, (size_t)NREL * H * 4,
                 hipMemcpyDeviceToDevice, stream);
  convw_kernel<<<320, 256, 0, stream>>>(w_neigh, w_loop, tg_w, wbt);
  l2norm_kernel<<<N_ENT / 4, 256, 0, stream>>>(emb_ent, out, hb);

  // batched CSR build for all timesteps
  hipMemsetAsync(rp8, 0, (size_t)T_STEPS * N_ENT * 4, stream);
  dim3 ge((NEDGE + 255) / 256, T_STEPS);
  indeg_all<<<ge, 256, 0, stream>>>(dst, rp8);
  reduce_all<<<dim3(NB196, T_STEPS), 256, 0, stream>>>(rp8, bsum8);
  scan_sums_all<<<T_STEPS, 256, 0, stream>>>(bsum8);
  scan_apply_all<<<dim3(NB196, T_STEPS), 256, 0, stream>>>(rp8, bsum8);
  scatter_all<<<ge, 256, 0, stream>>>(src, dst, ety, rp8, edges8);

  for (int t = 0; t < T_STEPS; t++) {
    float* h_t = out + (size_t)t * NH;
    float* h_n = out + (size_t)(t + 1) * NH;  // also scratch: relsum, then hB
    const int* rp = rp8 + (size_t)t * N_ENT;
    const u32* edges = edges8 + (size_t)t * NEDGE;
    float* relsum = h_n;

    relsum_kernel<<<N_ENT / 8, 256, 0, stream>>>(emb_rel, rp, edges, relsum);
    // layer 0
    gather_h<<<N_ENT / 8, 256, 0, stream>>>(hb, relsum, rp, edges, aggb);
    rgcn_gemm_mfma<0><<<(N_ENT + 63) / 64, 256, 0, stream>>>(
        aggb, hb, wbt, wbt + 16384, hAb, nullptr);
    fixup_kernel<1><<<256, 128, 0, stream>>>(hb, w_evolve, rp, hAb, nullptr);
    // layer 1
    gather_h<<<N_ENT / 8, 256, 0, stream>>>(hAb, relsum, rp, edges, aggb);
    rgcn_gemm_mfma<1><<<(N_ENT + 63) / 64, 256, 0, stream>>>(
        aggb, hAb, wbt + 32768, wbt + 49152, nullptr, h_n);
    fixup_kernel<0><<<256, 128, 0, stream>>>(hAb, w_evolve + 16384, rp, nullptr, h_n);
    // time gate + combine (in-place on h_n; also emits bf16 state for next step)
    gate_gemm_mfma<<<(N_ENT + 63) / 64, 256, 0, stream>>>(hb, wbt + 65536, tg_b, gateb);
    combine_kernel<<<N_ENT / 4, 256, 0, stream>>>(h_n, gateb, h_t, h_n, hb);
  }
}